// Round 5
// baseline (394.303 us; speedup 1.0000x reference)
//
#include <hip/hip_runtime.h>
#include <math.h>

// Codebook argmin via split-bf16 MFMA, m97-shaped block.
// cross = xh*ch + xh*cl + xl*ch  (3x v_mfma_f32_32x32x16_bf16).
// Block = 256 thr = 128 pixels x 512 clusters; clusters in 2 sequential
// halves of 256 (acc = 2mt x 4nt x 16 = 128 AGPR -> 2 waves/SIMD ->
// 2 blocks/CU; grid 512 = exactly 2/CU, balanced, cross-block overlap).
// x staged once per chunk into LDS (frag-ordered bf16 hi/lo planes);
// cluster frags from L2-resident ws. fp64 re-check of near-ties.

#define NK   512
#define NC   512
#define NHW  4096
#define PIXB 128
#define MARGIN 0.02f

typedef unsigned short u16;
typedef __attribute__((ext_vector_type(8)))  short  short8;
typedef __attribute__((ext_vector_type(8)))  unsigned short ushort8;
typedef __attribute__((ext_vector_type(16))) float  f32x16;

__device__ __forceinline__ u16 f2bf_rne(float f) {
    unsigned u = __builtin_bit_cast(unsigned, f);
    u += 0x7FFFu + ((u >> 16) & 1u);
    return (u16)(u >> 16);
}
__device__ __forceinline__ float bf2f(u16 h) {
    unsigned u = ((unsigned)h) << 16;
    return __builtin_bit_cast(float, u);
}

// wcc frag layout: [ch 32][unit 32][lane 64][8 bf16]; unit u<16 = hi plane of
// m-tile u, u>=16 = lo plane of m-tile u-16. lane ls: cluster k = mt*32+(ls&31),
// channels c = ch*16 + (ls>>5)*8 + j.
__global__ __launch_bounds__(256) void prep_pack(const float* __restrict__ cc,
                                                 u16* __restrict__ wcc) {
    const int g  = blockIdx.x * 256 + threadIdx.x;   // 65536 total
    const int ls = g & 63;
    const int u  = (g >> 6) & 31;
    const int ch = g >> 11;
    const int plane = u >> 4;
    const int mt    = u & 15;
    const int k  = mt * 32 + (ls & 31);
    const int c0 = ch * 16 + (ls >> 5) * 8;
    const float* row = cc + (size_t)k * NC + c0;
    short8 v;
    #pragma unroll
    for (int j = 0; j < 8; ++j) {
        float f = row[j];
        u16 h = f2bf_rne(f);
        v[j] = plane ? (short)f2bf_rne(f - bf2f(h)) : (short)h;
    }
    *(short8*)(wcc + (size_t)g * 8) = v;
}

__global__ __launch_bounds__(256) void prep_shalf(const float* __restrict__ cc,
                                                  float* __restrict__ shalf) {
    const int k    = blockIdx.x * 4 + (threadIdx.x >> 6);
    const int lane = threadIdx.x & 63;
    const float4* row = (const float4*)(cc + (size_t)k * NC);
    float s = 0.f;
    #pragma unroll
    for (int i = 0; i < 2; ++i) {
        float4 v = row[lane + i * 64];
        s = fmaf(v.x, v.x, s); s = fmaf(v.y, v.y, s);
        s = fmaf(v.z, v.z, s); s = fmaf(v.w, v.w, s);
    }
    #pragma unroll
    for (int off = 32; off > 0; off >>= 1) s += __shfl_down(s, off, 64);
    if (lane == 0) shalf[k] = 0.5f * s;
}

__global__ __launch_bounds__(256, 2) void codebook_mfma(
        const float* __restrict__ x,
        const float* __restrict__ cc,
        const u16* __restrict__ wcc,
        const float* __restrict__ shalf,
        int* __restrict__ out)
{
    __shared__ float sh_s[NK];                       // 2KB
    __shared__ __align__(16) u16 xsh[2][2][PIXB][8]; // [plane][oct][pix][8ch] 8KB
    __shared__ float cand_v[8][PIXB + 1];            // 4KB
    __shared__ float cand_s[8][PIXB + 1];
    __shared__ int   cand_k[8][PIXB + 1];
    __shared__ float xcol[NC];                       // 2KB
    __shared__ double dvv[256];                      // 2KB
    __shared__ int    dii[256];
    __shared__ int    flagsh[PIXB];
    __shared__ int    bestk_sh[PIXB];

    const int tid = threadIdx.x;
    const int w   = tid >> 6;
    const int l   = tid & 63;

    const int gp0 = blockIdx.x * PIXB;               // 128 | 4096: no batch crossing
    const float* xb = x + (size_t)(gp0 >> 12) * (NC * NHW) + (gp0 & (NHW - 1));

    sh_s[tid]       = shalf[tid];
    sh_s[tid + 256] = shalf[tid + 256];

    // staging role: thread owns (pixel sp, channel-octet soct) -> one B-frag
    const int soct = tid >> 7;                       // 0/1
    const int sp   = (tid & 63) + ((tid >> 6) & 1) * 64;
    const float* xsrc = xb + (size_t)(soct * 8) * NHW + sp;

    const int rg = l >> 5;                           // row-group within C/D

    float bestv[4] = {-INFINITY, -INFINITY, -INFINITY, -INFINITY};
    float secv [4] = {-INFINITY, -INFINITY, -INFINITY, -INFINITY};
    int   bkv  [4] = {0, 0, 0, 0};

    #pragma unroll 1
    for (int h = 0; h < 2; ++h) {
        f32x16 acc[2][4] = {};

        float nf[8];
        #pragma unroll
        for (int j = 0; j < 8; ++j)
            nf[j] = xsrc[(size_t)j * NHW];

        for (int ch = 0; ch < 32; ++ch) {
            // convert my 8 x-floats to bf16 hi/lo (registers only)
            unsigned hv[4], lv[4];
            #pragma unroll
            for (int j = 0; j < 4; ++j) {
                float f0 = nf[2 * j], f1 = nf[2 * j + 1];
                unsigned u0 = __builtin_bit_cast(unsigned, f0);
                unsigned u1 = __builtin_bit_cast(unsigned, f1);
                float r0 = f0 - __builtin_bit_cast(float, u0 & 0xFFFF0000u);
                float r1 = f1 - __builtin_bit_cast(float, u1 & 0xFFFF0000u);
                hv[j] = (u0 >> 16) | (u1 & 0xFFFF0000u);
                lv[j] = (__builtin_bit_cast(unsigned, r0) >> 16) |
                        (__builtin_bit_cast(unsigned, r1) & 0xFFFF0000u);
            }
            __syncthreads();                         // xsh free (prev chunk read)
            *(uint4*)&xsh[0][soct][sp][0] = make_uint4(hv[0], hv[1], hv[2], hv[3]);
            *(uint4*)&xsh[1][soct][sp][0] = make_uint4(lv[0], lv[1], lv[2], lv[3]);
            __syncthreads();                         // xsh ready
            // prefetch next chunk's x (overlaps A-loads/ds/MFMA below)
            if (ch < 31) {
                #pragma unroll
                for (int j = 0; j < 8; ++j)
                    nf[j] = xsrc[(size_t)((ch + 1) * 16 + j) * NHW];
            }
            // A frags (L2-resident ws, base + lane*16, coalesced)
            short8 ah[2], al[2];
            #pragma unroll
            for (int j2 = 0; j2 < 2; ++j2) {
                const int gm = h * 8 + w * 2 + j2;
                ah[j2] = *(const short8*)(wcc + ((size_t)(ch * 32 + gm)      * 64 + l) * 8);
                al[j2] = *(const short8*)(wcc + ((size_t)(ch * 32 + 16 + gm) * 64 + l) * 8);
            }
            // B frags from LDS (conflict-free b128)
            short8 bh[4], bl[4];
            #pragma unroll
            for (int nt = 0; nt < 4; ++nt) {
                bh[nt] = *(const short8*)&xsh[0][rg][nt * 32 + (l & 31)][0];
                bl[nt] = *(const short8*)&xsh[1][rg][nt * 32 + (l & 31)][0];
            }
            // term-major: 8 independent accumulators per term (dep dist 8)
            #pragma unroll
            for (int j2 = 0; j2 < 2; ++j2)
                #pragma unroll
                for (int nt = 0; nt < 4; ++nt)
                    acc[j2][nt] = __builtin_amdgcn_mfma_f32_32x32x16_bf16(ah[j2], bh[nt], acc[j2][nt], 0, 0, 0);
            #pragma unroll
            for (int j2 = 0; j2 < 2; ++j2)
                #pragma unroll
                for (int nt = 0; nt < 4; ++nt)
                    acc[j2][nt] = __builtin_amdgcn_mfma_f32_32x32x16_bf16(al[j2], bh[nt], acc[j2][nt], 0, 0, 0);
            #pragma unroll
            for (int j2 = 0; j2 < 2; ++j2)
                #pragma unroll
                for (int nt = 0; nt < 4; ++nt)
                    acc[j2][nt] = __builtin_amdgcn_mfma_f32_32x32x16_bf16(ah[j2], bl[nt], acc[j2][nt], 0, 0, 0);
        }

        // extract per-lane top-2 for this half (carried in registers)
        #pragma unroll
        for (int nt = 0; nt < 4; ++nt) {
            #pragma unroll
            for (int j2 = 0; j2 < 2; ++j2) {
                const int kbase = h * 256 + (w * 2 + j2) * 32 + 4 * rg;
                #pragma unroll
                for (int reg = 0; reg < 16; ++reg) {
                    const int k = kbase + (reg & 3) + 8 * (reg >> 2);
                    const float v = acc[j2][nt][reg] - sh_s[k];
                    if (v > bestv[nt]) { secv[nt] = bestv[nt]; bestv[nt] = v; bkv[nt] = k; }
                    else if (v > secv[nt]) secv[nt] = v;
                }
            }
        }
    }

    // ---- combine across lanes: 8 slots per pixel ----
    #pragma unroll
    for (int nt = 0; nt < 4; ++nt) {
        const int pc   = nt * 32 + (l & 31);
        const int slot = w * 2 + rg;
        cand_v[slot][pc] = bestv[nt];
        cand_s[slot][pc] = secv[nt];
        cand_k[slot][pc] = bkv[nt];
    }
    __syncthreads();

    if (tid < PIXB) {
        float best = -INFINITY, sec = -INFINITY;
        int bk = 1 << 30;
        #pragma unroll
        for (int s = 0; s < 8; ++s) {
            float v  = cand_v[s][tid];
            float v2 = cand_s[s][tid];
            int  kk  = cand_k[s][tid];
            if (v > best || (v == best && kk < bk)) {
                sec = fmaxf(sec, best);
                best = v; bk = kk;
            } else sec = fmaxf(sec, v);
            sec = fmaxf(sec, v2);
        }
        bestk_sh[tid] = bk;
        flagsh[tid] = (best - sec < MARGIN) ? 1 : 0;
    }
    __syncthreads();

    // fp64 full re-check for near-tie pixels (rare)
    for (int pix = 0; pix < PIXB; ++pix) {
        if (!flagsh[pix]) continue;              // uniform (LDS) branch
        for (int c = tid; c < NC; c += 256)
            xcol[c] = xb[(size_t)c * NHW + pix];
        __syncthreads();
        double bd = 1e300;
        int bkk = 1 << 30;
        #pragma unroll
        for (int r = 0; r < 2; ++r) {
            const int k = tid + r * 256;
            const float4* crow = (const float4*)(cc + (size_t)k * NC);
            const float4* xc4  = (const float4*)xcol;
            double d = 0.0;
            for (int c4 = 0; c4 < NC / 4; ++c4) {
                float4 cv = crow[c4], xv = xc4[c4];
                double d0 = (double)xv.x - (double)cv.x;
                double d1 = (double)xv.y - (double)cv.y;
                double d2 = (double)xv.z - (double)cv.z;
                double d3 = (double)xv.w - (double)cv.w;
                d = fma(d0, d0, d); d = fma(d1, d1, d);
                d = fma(d2, d2, d); d = fma(d3, d3, d);
            }
            if (d < bd || (d == bd && k < bkk)) { bd = d; bkk = k; }
        }
        dvv[tid] = bd; dii[tid] = bkk;
        __syncthreads();
        for (int srd = 128; srd > 0; srd >>= 1) {
            if (tid < srd) {
                double ov = dvv[tid + srd]; int oi = dii[tid + srd];
                if (ov < dvv[tid] || (ov == dvv[tid] && oi < dii[tid])) {
                    dvv[tid] = ov; dii[tid] = oi;
                }
            }
            __syncthreads();
        }
        if (tid == 0) bestk_sh[pix] = dii[0];
        __syncthreads();
    }

    if (tid < PIXB) out[gp0 + tid] = bestk_sh[tid];
}

extern "C" void kernel_launch(void* const* d_in, const int* in_sizes, int n_in,
                              void* d_out, int out_size, void* d_ws, size_t ws_size,
                              hipStream_t stream) {
    const float* x  = (const float*)d_in[0];   // (16, 512, 64, 64) f32
    const float* cc = (const float*)d_in[1];   // (1, 512, 512, 1, 1) f32
    int* out = (int*)d_out;                    // (16, 1, 64, 64) int32

    float* shalf = (float*)d_ws;               // 512 floats
    u16*   wcc   = (u16*)(shalf + NK);         // 1MB frag-ordered hi/lo bf16

    prep_shalf<<<NK / 4, 256, 0, stream>>>(cc, shalf);
    prep_pack<<<(32 * 32 * 64) / 256, 256, 0, stream>>>(cc, wcc);
    codebook_mfma<<<(16 * NHW) / PIXB, 256, 0, stream>>>(x, cc, wcc, shalf, out);
}